// Round 13
// baseline (462.053 us; speedup 1.0000x reference)
//
#include <hip/hip_runtime.h>
#include <stdint.h>

#define A_DIM 8192
#define B_DIM 8192
#define K_CL  256
#define NSLAB 8
#define SLABW 1024              // k-columns per slab
#define NKS   32                // K-steps of 32 per slab

typedef short bf16x8 __attribute__((ext_vector_type(8)));
typedef float f32x4  __attribute__((ext_vector_type(4)));
typedef float f32x16 __attribute__((ext_vector_type(16)));
typedef unsigned short u16;

__device__ __forceinline__ u16 f2bf(float f) {
    unsigned int u = __float_as_uint(f);
    u += 0x7fffu + ((u >> 16) & 1u);   // RNE (prep only)
    return (u16)(u >> 16);
}

// ---------- PROBE 1: w read, EXACT production fragment pattern, 5 passes ----------
__global__ __launch_bounds__(256) void k_probe_pat(const float* __restrict__ w,
                                                   float* __restrict__ dump) {
    const int bid = blockIdx.x;
    const int slab = bid & 7;
    const int m0w = (bid >> 3) * 128 + (threadIdx.x >> 6) * 32;
    const int lane = threadIdx.x & 63;
    const int l31 = lane & 31, half = lane >> 5;
    const float* wrow = w + (size_t)(m0w + l31) * B_DIM + slab * SLABW + half * 8;

    f32x4 s0 = {0,0,0,0}, s1 = {0,0,0,0}, s2 = {0,0,0,0}, s3 = {0,0,0,0};
    for (int pass = 0; pass < 5; ++pass) {
#pragma unroll 8
        for (int s = 0; s < NKS; ++s) {
            s0 += *(const f32x4*)(wrow + s * 32);
            s1 += *(const f32x4*)(wrow + s * 32 + 4);
            s2 += *(const f32x4*)(wrow + s * 32 + 16);
            s3 += *(const f32x4*)(wrow + s * 32 + 20);
        }
        asm volatile("" ::: "memory");   // force reloads each pass (defeat CSE)
    }
    f32x4 t = s0 + s1 + s2 + s3;
    dump[bid * 256 + threadIdx.x] = t[0] + t[1] + t[2] + t[3];
}

// ---------- PROBE 2: w read, fully linear (1 KB/instr per wave), 5 passes ----------
__global__ __launch_bounds__(256) void k_probe_lin(const float* __restrict__ w,
                                                   float* __restrict__ dump) {
    const int gw = blockIdx.x * 4 + (threadIdx.x >> 6);   // 0..2047, 128 KB each
    const int lane = threadIdx.x & 63;
    const float* base = w + (size_t)gw * 32768 + lane * 4;

    f32x4 acc = {0,0,0,0};
    for (int pass = 0; pass < 5; ++pass) {
#pragma unroll 8
        for (int i = 0; i < 128; ++i)
            acc += *(const f32x4*)(base + i * 256);
        asm volatile("" ::: "memory");
    }
    dump[blockIdx.x * 256 + threadIdx.x] = acc[0] + acc[1] + acc[2] + acc[3];
}

// ---------- prep: pack p_r into 32x32x16 MFMA B-fragment layout, bf16 ----------
__global__ __launch_bounds__(256) void k_prep(const float* __restrict__ pr,
                                              u16* __restrict__ Bpack,
                                              float* __restrict__ out) {
    const int kb2 = blockIdx.x;          // 0..511
    const int t = threadIdx.x;
    if (kb2 == 0 && t == 0) out[0] = 0.0f;
    const int lane = t & 63, wv = t >> 6;
    const int l31 = lane & 31, half = lane >> 5;
#pragma unroll
    for (int ci = 0; ci < 2; ci++) {
        const int c2 = wv * 2 + ci;
        float v[8];
#pragma unroll
        for (int j = 0; j < 8; j++)
            v[j] = pr[(size_t)(kb2 * 16 + half * 8 + j) * K_CL + c2 * 32 + l31];
        union { bf16x8 b; unsigned int u[4]; } o;
#pragma unroll
        for (int j = 0; j < 4; j++)
            o.u[j] = (unsigned int)f2bf(v[2 * j]) | ((unsigned int)f2bf(v[2 * j + 1]) << 16);
        *(bf16x8*)(Bpack + ((size_t)(kb2 * 8 + c2) * 64 + lane) * 8) = o.b;
    }
}

// ---------- main: unchanged r12 body (passed, absmax 0) ----------
__global__ __launch_bounds__(256, 2) void k_main(const float* __restrict__ w,
                                                 const float* __restrict__ pl,
                                                 const u16* __restrict__ Bpack,
                                                 const float* __restrict__ cp,
                                                 float* __restrict__ out) {
    __shared__ u16 Bl[2][8192];
    __shared__ float rowsum_s[4][32];
    __shared__ float red[4];

    const int bid = blockIdx.x;
    const int slab = bid & 7;
    const int m0b = (bid >> 3) * 128;
    const int tid = threadIdx.x;
    const int lane = tid & 63, wv = tid >> 6;
    const int l31 = lane & 31, half = lane >> 5;
    const int m0w = m0b + wv * 32;

    const float* wrow = w + (size_t)(m0w + l31) * B_DIM + slab * SLABW + half * 8;
    const char* bsrc = (const char*)Bpack + (size_t)slab * 64 * 8192;

    f32x16 acc[8];
#pragma unroll
    for (int i = 0; i < 8; i++)
#pragma unroll
        for (int r = 0; r < 16; r++) acc[i][r] = 0.f;
    float sm = 0.f;

    f32x4 Ga[4], Gb[4];

#define SB0 __builtin_amdgcn_sched_barrier(0)
#define WAITV(n) do { asm volatile("s_waitcnt vmcnt(" #n ")" ::: "memory"); SB0; } while (0)
#define BAR do { __builtin_amdgcn_s_barrier(); SB0; } while (0)

#define STAGEB(bufi, s_) do {                                                            \
        const char* sp_ = bsrc + (size_t)(s_) * 16384 + tid * 16;                        \
        char* dp_ = (char*)&Bl[(bufi)][0] + tid * 16;                                    \
        _Pragma("unroll")                                                                \
        for (int j_ = 0; j_ < 4; j_++)                                                   \
            __builtin_amdgcn_global_load_lds(                                            \
                (const __attribute__((address_space(1))) void*)(sp_ + j_ * 4096),        \
                (__attribute__((address_space(3))) void*)(dp_ + j_ * 4096), 16, 0, 0);   \
        SB0;                                                                             \
    } while (0)

#define GLOADA(GS, s_) do {                                                              \
        GS[0] = *(const f32x4*)(wrow + (s_) * 32);                                       \
        GS[1] = *(const f32x4*)(wrow + (s_) * 32 + 4);                                   \
        GS[2] = *(const f32x4*)(wrow + (s_) * 32 + 16);                                  \
        GS[3] = *(const f32x4*)(wrow + (s_) * 32 + 20);                                  \
        SB0;                                                                             \
    } while (0)

#define PERM2(hi, lo) __builtin_amdgcn_perm(__float_as_uint(hi), __float_as_uint(lo), 0x07060302u)

#define KF(GS, i0, i1, kf_, lb_) do {                                                    \
        union { bf16x8 v; unsigned int u[4]; } a_;                                       \
        a_.u[0] = PERM2(GS[i0][1], GS[i0][0]);                                           \
        a_.u[1] = PERM2(GS[i0][3], GS[i0][2]);                                           \
        a_.u[2] = PERM2(GS[i1][1], GS[i1][0]);                                           \
        a_.u[3] = PERM2(GS[i1][3], GS[i1][2]);                                           \
        sm += GS[i0][0] + GS[i0][1] + GS[i0][2] + GS[i0][3]                              \
            + GS[i1][0] + GS[i1][1] + GS[i1][2] + GS[i1][3];                             \
        const u16* bb_ = (lb_) + (kf_) * 4096 + lane * 8;                                \
        _Pragma("unroll")                                                                \
        for (int c_ = 0; c_ < 8; c_++) {                                                 \
            bf16x8 bf_ = *(const bf16x8*)(bb_ + c_ * 512);                               \
            acc[c_] = __builtin_amdgcn_mfma_f32_32x32x16_bf16(a_.v, bf_, acc[c_], 0, 0, 0); \
        }                                                                                \
    } while (0)

#define STEP(s_, GC) do {                                                                \
        STAGEB(((s_) + 1) & 1, (s_) + 1);                                                \
        const u16* lb_ = &Bl[(s_) & 1][0];                                               \
        KF(GC, 0, 1, 0, lb_);                                                            \
        KF(GC, 2, 3, 1, lb_);                                                            \
        GLOADA(GC, (s_) + 2);                                                            \
        WAITV(4);                                                                        \
        BAR;                                                                             \
    } while (0)

    STAGEB(0, 0);
    GLOADA(Ga, 0);
    GLOADA(Gb, 1);
    WAITV(4);
    BAR;

    for (int s = 0; s < 30; s += 2) {
        STEP(s, Ga);
        STEP(s + 1, Gb);
    }
    {
        STAGEB(1, 31);
        const u16* lb_ = &Bl[0][0];
        KF(Ga, 0, 1, 0, lb_);
        KF(Ga, 2, 3, 1, lb_);
        WAITV(0);
        BAR;
    }
    {
        const u16* lb_ = &Bl[1][0];
        KF(Gb, 0, 1, 0, lb_);
        KF(Gb, 2, 3, 1, lb_);
    }

#undef STEP
#undef KF
#undef PERM2
#undef GLOADA
#undef STAGEB

    {
        float v = sm + __shfl_xor(sm, 32, 64);
        if (lane < 32) rowsum_s[wv][l31] = v;
    }

    float rcp_cp[8];
#pragma unroll
    for (int c2 = 0; c2 < 8; c2++)
        rcp_cp[c2] = 1.0f / cp[c2 * 32 + l31];

    float tot = 0.f;
#pragma unroll
    for (int reg = 0; reg < 16; reg++) {
        const int lrow = (reg & 3) + 8 * (reg >> 2) + 4 * half;
        const float rs = rowsum_s[wv][lrow];
        const float* plrow = pl + (size_t)(m0w + lrow) * K_CL + l31;
#pragma unroll
        for (int c2 = 0; c2 < 8; c2++) {
            const float q = acc[c2][reg];
            const float p = plrow[c2 * 32];
            tot += (q + p * (rs - 2.0f * q)) * rcp_cp[c2];
        }
    }
    for (int o = 32; o; o >>= 1) tot += __shfl_down(tot, o, 64);
    if (lane == 0) red[wv] = tot;
    __syncthreads();
    if (tid == 0) atomicAdd(out, red[0] + red[1] + red[2] + red[3]);

#undef WAITV
#undef BAR
#undef SB0
}

extern "C" void kernel_launch(void* const* d_in, const int* in_sizes, int n_in,
                              void* d_out, int out_size, void* d_ws, size_t ws_size,
                              hipStream_t stream) {
    const float* w  = (const float*)d_in[0];
    const float* pl = (const float*)d_in[1];
    const float* pr = (const float*)d_in[2];
    const float* cp = (const float*)d_in[3];
    float* out = (float*)d_out;

    u16* Bpack = (u16*)d_ws;                                          // 4 MB
    float* dump = (float*)((char*)d_ws + (size_t)8 * 1024 * 1024);    // probe sink

    k_probe_pat<<<dim3(512), dim3(256), 0, stream>>>(w, dump);
    k_probe_lin<<<dim3(512), dim3(256), 0, stream>>>(w, dump + 512 * 256);
    k_prep<<<dim3(512), dim3(256), 0, stream>>>(pr, Bpack, out);
    k_main<<<dim3(64 * NSLAB), dim3(256), 0, stream>>>(w, pl, Bpack, cp, out);
}

// Round 14
// 76.732 us; speedup vs baseline: 6.0216x; 6.0216x over previous
//
#include <hip/hip_runtime.h>
#include <stdint.h>

#define A_DIM 8192
#define B_DIM 8192
#define K_CL  256
#define NSTEP 32                // k-steps of 256 f32 over the full 8192 columns

typedef short bf16x8 __attribute__((ext_vector_type(8)));
typedef float f32x4  __attribute__((ext_vector_type(4)));
typedef float f32x16 __attribute__((ext_vector_type(16)));
typedef unsigned short u16;

__device__ __forceinline__ u16 f2bf(float f) {
    unsigned int u = __float_as_uint(f);
    u += 0x7fffu + ((u >> 16) & 1u);   // RNE (prep only)
    return (u16)(u >> 16);
}

// ---------- prep: pack p_r into 32x32x16 MFMA B-fragment layout, bf16 ----------
// Bpack[((kb2*8 + c2)*64 + lane)*8 + j] = bf16(p_r[kb2*16 + (lane>>5)*8 + j][c2*32 + (lane&31)])
__global__ __launch_bounds__(256) void k_prep(const float* __restrict__ pr,
                                              u16* __restrict__ Bpack,
                                              float* __restrict__ out) {
    const int kb2 = blockIdx.x;          // 0..511
    const int t = threadIdx.x;
    if (kb2 == 0 && t == 0) out[0] = 0.0f;
    const int lane = t & 63, wv = t >> 6;
    const int l31 = lane & 31, half = lane >> 5;
#pragma unroll
    for (int ci = 0; ci < 2; ci++) {
        const int c2 = wv * 2 + ci;
        float v[8];
#pragma unroll
        for (int j = 0; j < 8; j++)
            v[j] = pr[(size_t)(kb2 * 16 + half * 8 + j) * K_CL + c2 * 32 + l31];
        union { bf16x8 b; unsigned int u[4]; } o;
#pragma unroll
        for (int j = 0; j < 4; j++)
            o.u[j] = (unsigned int)f2bf(v[2 * j]) | ((unsigned int)f2bf(v[2 * j + 1]) << 16);
        *(bf16x8*)(Bpack + ((size_t)(kb2 * 8 + c2) * 64 + lane) * 8) = o.b;
    }
}

// ---------- main: page-local w stream (1 KB contiguous per instr, 4 rows/wave),
//            full-k sweep, 3-deep B quads, traced vmcnt queue ----------
__global__ __launch_bounds__(512, 2) void k_main(const float* __restrict__ w,
                                                 const float* __restrict__ pl,
                                                 const u16* __restrict__ Bpack,
                                                 const float* __restrict__ cp,
                                                 float* __restrict__ out) {
    __shared__ u16 Abuf[2][32 * 256];    // 2 x 16 KB bf16 tile [32 rows][512 B], XOR-swizzled
    __shared__ float rowsum_s[32];
    __shared__ float red[8];

    const int bid = blockIdx.x;          // 0..255 -> 32-row stripe, full k
    const int m0 = bid * 32;
    const int tid = threadIdx.x;
    const int lane = tid & 63, wv = tid >> 6;     // wv = 0..7
    const int l31 = lane & 31, half = lane >> 5;

    // A staging: wave wv owns rows wv*4..+3; instr j = row wv*4+j, lane covers f32 cols lane*4..+3
    const float* wthr = w + (size_t)(m0 + wv * 4) * B_DIM + lane * 4;

    int wb[4];                           // LDS write byte offsets (8 B per lane per row)
#pragma unroll
    for (int j = 0; j < 4; j++) {
        const int row = wv * 4 + j;
        wb[j] = row * 512 + ((lane * 8) ^ ((row & 31) << 4));
    }

    f32x16 acc;                          // 32 rows x clusters wv*32+l31
#pragma unroll
    for (int r = 0; r < 16; r++) acc[r] = 0.f;
    float sm[4] = {0.f, 0.f, 0.f, 0.f};

    f32x4 GA[4], GB[4];
    bf16x8 Q0[4], Q1[4], Q2[4], Q3[4];

#define SB0 __builtin_amdgcn_sched_barrier(0)
#define WAITV(n) do { asm volatile("s_waitcnt vmcnt(" #n ")" ::: "memory"); SB0; } while (0)
#define LGKM0BAR do { asm volatile("s_waitcnt lgkmcnt(0)" ::: "memory"); \
                      __builtin_amdgcn_s_barrier(); SB0; } while (0)

#define GLOADA(GS, s_) do {                                                              \
        _Pragma("unroll")                                                                \
        for (int j_ = 0; j_ < 4; j_++)                                                   \
            GS[j_] = *(const f32x4*)(wthr + (size_t)j_ * B_DIM + (size_t)(s_) * 256);    \
        SB0;                                                                             \
    } while (0)

#define LOADQ(Qs, s_, q_) do {                                                           \
        _Pragma("unroll")                                                                \
        for (int i_ = 0; i_ < 4; i_++)                                                   \
            Qs[i_] = *(const bf16x8*)(Bpack +                                            \
                (size_t)(((s_) * 16 + (q_) * 4 + i_) * 8 + wv) * 512 + lane * 8);        \
        SB0;                                                                             \
    } while (0)

#define PERM2(hi, lo) __builtin_amdgcn_perm(__float_as_uint(hi), __float_as_uint(lo), 0x07060302u)

#define CONV(GS, bufi) do {                                                              \
        char* lb_ = (char*)&Abuf[(bufi)][0];                                             \
        _Pragma("unroll")                                                                \
        for (int j_ = 0; j_ < 4; j_++) {                                                 \
            sm[j_] += GS[j_][0] + GS[j_][1] + GS[j_][2] + GS[j_][3];                     \
            uint2 p_;                                                                    \
            p_.x = PERM2(GS[j_][1], GS[j_][0]);                                          \
            p_.y = PERM2(GS[j_][3], GS[j_][2]);                                          \
            *(uint2*)(lb_ + wb[j_]) = p_;                                                \
        }                                                                                \
    } while (0)

#define QUAD(q_, Qs, bufi) do {                                                          \
        const char* ab_ = (const char*)&Abuf[(bufi)][0] + l31 * 512;                     \
        _Pragma("unroll")                                                                \
        for (int i_ = 0; i_ < 4; i_++) {                                                 \
            const int kf_ = (q_) * 4 + i_;                                               \
            bf16x8 a_ = *(const bf16x8*)(ab_ + ((kf_ * 32 + half * 16) ^ (l31 << 4)));   \
            acc = __builtin_amdgcn_mfma_f32_32x32x16_bf16(a_, Qs[i_], acc, 0, 0, 0);     \
        }                                                                                \
        SB0;                                                                             \
    } while (0)

// entry invariant at step s: queue = [Q0(s):4][A(s+1):4]
#define BODY(s_, GC, GN, DOA, DOB0, W2, W5, W9, W12) do {                                \
        LOADQ(Q1, s_, 1); LOADQ(Q2, s_, 2);                                              \
        WAITV(W2);                       /* retire Q0(s) — issued a full step ago */     \
        QUAD(0, Q0, (s_) & 1);                                                           \
        LOADQ(Q3, s_, 3);                                                                \
        WAITV(W5);                       /* retire A(s+1) (old) + Q1 */                  \
        CONV(GC, ((s_) + 1) & 1);                                                        \
        QUAD(1, Q1, (s_) & 1);                                                           \
        if (DOB0) LOADQ(Q0, (s_) + 1, 0);                                                \
        WAITV(W9);                       /* retire Q2 */                                 \
        QUAD(2, Q2, (s_) & 1);                                                           \
        if (DOA) GLOADA(GN, (s_) + 2);                                                   \
        WAITV(W12);                      /* retire Q3; Q0',A' cross barrier in flight */ \
        QUAD(3, Q3, (s_) & 1);                                                           \
        LGKM0BAR;                                                                        \
    } while (0)

    // prologue -> entry invariant for s=0
    GLOADA(GA, 0);                       // A(0)
    LOADQ(Q0, 0, 0);                     // Q0(0)
    GLOADA(GB, 1);                       // A(1)
    WAITV(8);                            // retire A(0)
    CONV(GA, 0);                         // tile 0 -> buf0
    LGKM0BAR;

    for (int s = 0; s < 30; s += 2) {    // s = 0..29
        BODY(s,     GB, GA, 1, 1, 12, 8, 8, 8);
        BODY(s + 1, GA, GB, 1, 1, 12, 8, 8, 8);
    }
    BODY(30, GB, GA, 0, 1, 12, 8, 8, 4); // converts A(31); loads Q0(31); no A(32)
    // step 31: compute only, buf1
    {
        LOADQ(Q1, 31, 1); LOADQ(Q2, 31, 2);
        WAITV(8);  QUAD(0, Q0, 1);
        LOADQ(Q3, 31, 3);
        WAITV(8);  QUAD(1, Q1, 1);
        WAITV(4);  QUAD(2, Q2, 1);
        WAITV(0);  QUAD(3, Q3, 1);
    }

#undef BODY
#undef QUAD
#undef CONV
#undef PERM2
#undef LOADQ
#undef GLOADA

    // full-k row sums: all 64 lanes hold partials of row wv*4+j
#pragma unroll
    for (int j = 0; j < 4; j++) {
        float v = sm[j];
#pragma unroll
        for (int o = 1; o <= 32; o <<= 1) v += __shfl_xor(v, o, 64);
        if (lane == 0) rowsum_s[wv * 4 + j] = v;
    }
    __syncthreads();

    // epilogue: tot = sum over (row, cluster) of [q + p*(rs - 2q)] / cp
    // C/D 32x32: col = lane&31, row = (reg&3) + 8*(reg>>2) + 4*(lane>>5)
    const float rcp = 1.0f / cp[wv * 32 + l31];
    float tot = 0.f;
#pragma unroll
    for (int reg = 0; reg < 16; reg++) {
        const int lrow = (reg & 3) + 8 * (reg >> 2) + 4 * half;
        const float rs = rowsum_s[lrow];
        const float p = pl[(size_t)(m0 + lrow) * K_CL + wv * 32 + l31];
        const float q = acc[reg];
        tot += (q + p * (rs - 2.0f * q)) * rcp;
    }
    for (int o = 32; o; o >>= 1) tot += __shfl_down(tot, o, 64);
    if (lane == 0) red[wv] = tot;
    __syncthreads();
    if (tid == 0) {
        float s = 0.f;
#pragma unroll
        for (int i = 0; i < 8; i++) s += red[i];
        atomicAdd(out, s);
    }

#undef WAITV
#undef LGKM0BAR
#undef SB0
}

extern "C" void kernel_launch(void* const* d_in, const int* in_sizes, int n_in,
                              void* d_out, int out_size, void* d_ws, size_t ws_size,
                              hipStream_t stream) {
    const float* w  = (const float*)d_in[0];
    const float* pl = (const float*)d_in[1];
    const float* pr = (const float*)d_in[2];
    const float* cp = (const float*)d_in[3];
    float* out = (float*)d_out;

    u16* Bpack = (u16*)d_ws;   // 4 MB

    k_prep<<<dim3(512), dim3(256), 0, stream>>>(pr, Bpack, out);
    k_main<<<dim3(A_DIM / 32), dim3(512), 0, stream>>>(w, pl, Bpack, cp, out);
}

// Round 15
// 74.696 us; speedup vs baseline: 6.1858x; 1.0273x over previous
//
#include <hip/hip_runtime.h>
#include <stdint.h>

#define A_DIM 8192
#define B_DIM 8192
#define K_CL  256
#define NSLAB 8
#define SLABW 1024              // k-columns per slab
#define NKS   32                // K-steps of 32 per slab

typedef short bf16x8 __attribute__((ext_vector_type(8)));
typedef float f32x4  __attribute__((ext_vector_type(4)));
typedef float f32x16 __attribute__((ext_vector_type(16)));
typedef unsigned short u16;

__device__ __forceinline__ u16 f2bf(float f) {
    unsigned int u = __float_as_uint(f);
    u += 0x7fffu + ((u >> 16) & 1u);   // RNE (prep only)
    return (u16)(u >> 16);
}

// ---------- prep: pack p_r into 32x32x16 MFMA B-fragment layout, bf16 ----------
// Bpack[((kb2*8 + c2)*64 + lane)*8 + j] = bf16(p_r[kb2*16 + (lane>>5)*8 + j][c2*32 + (lane&31)])
__global__ __launch_bounds__(256) void k_prep(const float* __restrict__ pr,
                                              u16* __restrict__ Bpack,
                                              float* __restrict__ out) {
    const int kb2 = blockIdx.x;          // 0..511
    const int t = threadIdx.x;
    if (kb2 == 0 && t == 0) out[0] = 0.0f;
    const int lane = t & 63, wv = t >> 6;
    const int l31 = lane & 31, half = lane >> 5;
#pragma unroll
    for (int ci = 0; ci < 2; ci++) {
        const int c2 = wv * 2 + ci;
        float v[8];
#pragma unroll
        for (int j = 0; j < 8; j++)
            v[j] = pr[(size_t)(kb2 * 16 + half * 8 + j) * K_CL + c2 * 32 + l31];
        union { bf16x8 b; unsigned int u[4]; } o;
#pragma unroll
        for (int j = 0; j < 4; j++)
            o.u[j] = (unsigned int)f2bf(v[2 * j]) | ((unsigned int)f2bf(v[2 * j + 1]) << 16);
        *(bf16x8*)(Bpack + ((size_t)(kb2 * 8 + c2) * 64 + lane) * 8) = o.b;
    }
}

// ---------- main: r12 body + 3-set rotating A prefetch (2 steps deep, floor 8 KB/wave) ----------
__global__ __launch_bounds__(256, 2) void k_main(const float* __restrict__ w,
                                                 const float* __restrict__ pl,
                                                 const u16* __restrict__ Bpack,
                                                 const float* __restrict__ cp,
                                                 float* __restrict__ out) {
    __shared__ u16 Bl[2][8192];          // 2 x 16 KB ring (one K-step of B frags each)
    __shared__ float rowsum_s[4][32];
    __shared__ float red[4];

    const int bid = blockIdx.x;
    const int slab = bid & 7;            // XCD-pinned 512 KB Bpack slice
    const int m0b = (bid >> 3) * 128;
    const int tid = threadIdx.x;
    const int lane = tid & 63, wv = tid >> 6;
    const int l31 = lane & 31, half = lane >> 5;
    const int m0w = m0b + wv * 32;       // this wave's 32 rows

    const float* wrow = w + (size_t)(m0w + l31) * B_DIM + slab * SLABW + half * 8;
    const char* bsrc = (const char*)Bpack + (size_t)slab * 64 * 8192;

    f32x16 acc[8];                       // c2 = 0..7 (all 256 cols), rows = wave's 32
#pragma unroll
    for (int i = 0; i < 8; i++)
#pragma unroll
        for (int r = 0; r < 16; r++) acc[i][r] = 0.f;
    float sm = 0.f;

    f32x4 Ga[4], Gb[4], Gc[4];           // 3 rotating A sets: A(s), A(s+1), A(s+2)

#define SB0 __builtin_amdgcn_sched_barrier(0)
#define WAITV(n) do { asm volatile("s_waitcnt vmcnt(" #n ")" ::: "memory"); SB0; } while (0)
#define BAR do { __builtin_amdgcn_s_barrier(); SB0; } while (0)

#define STAGEB(bufi, s_) do {                                                            \
        const char* sp_ = bsrc + (size_t)(s_) * 16384 + tid * 16;                        \
        char* dp_ = (char*)&Bl[(bufi)][0] + tid * 16;                                    \
        _Pragma("unroll")                                                                \
        for (int j_ = 0; j_ < 4; j_++)                                                   \
            __builtin_amdgcn_global_load_lds(                                            \
                (const __attribute__((address_space(1))) void*)(sp_ + j_ * 4096),        \
                (__attribute__((address_space(3))) void*)(dp_ + j_ * 4096), 16, 0, 0);   \
        SB0;                                                                             \
    } while (0)

#define GLOADA(GS, s_) do {                                                              \
        GS[0] = *(const f32x4*)(wrow + (s_) * 32);                                       \
        GS[1] = *(const f32x4*)(wrow + (s_) * 32 + 4);                                   \
        GS[2] = *(const f32x4*)(wrow + (s_) * 32 + 16);                                  \
        GS[3] = *(const f32x4*)(wrow + (s_) * 32 + 20);                                  \
        SB0;                                                                             \
    } while (0)

#define PERM2(hi, lo) __builtin_amdgcn_perm(__float_as_uint(hi), __float_as_uint(lo), 0x07060302u)

#define KF(GS, i0, i1, kf_, lb_) do {                                                    \
        union { bf16x8 v; unsigned int u[4]; } a_;                                       \
        a_.u[0] = PERM2(GS[i0][1], GS[i0][0]);                                           \
        a_.u[1] = PERM2(GS[i0][3], GS[i0][2]);                                           \
        a_.u[2] = PERM2(GS[i1][1], GS[i1][0]);                                           \
        a_.u[3] = PERM2(GS[i1][3], GS[i1][2]);                                           \
        sm += GS[i0][0] + GS[i0][1] + GS[i0][2] + GS[i0][3]                              \
            + GS[i1][0] + GS[i1][1] + GS[i1][2] + GS[i1][3];                             \
        const u16* bb_ = (lb_) + (kf_) * 4096 + lane * 8;                                \
        _Pragma("unroll")                                                                \
        for (int c_ = 0; c_ < 8; c_++) {                                                 \
            bf16x8 bf_ = *(const bf16x8*)(bb_ + c_ * 512);                               \
            acc[c_] = __builtin_amdgcn_mfma_f32_32x32x16_bf16(a_.v, bf_, acc[c_], 0, 0, 0); \
        }                                                                                \
    } while (0)

// entry invariant at step s: outstanding = [A(s+1):4][A(s+2):4]; GC holds A(s) resident.
// Step: +B(s+1), compute, +A(s+3); WAITV(8) retires exactly {A(s+1), B(s+1)};
// floor outstanding = 8 KB/wave (64 KB/CU) across the barrier.
#define STEP(s_, GC, WN, DOA, DOB) do {                                                  \
        if (DOB) STAGEB(((s_) + 1) & 1, (s_) + 1);                                       \
        const u16* lb_ = &Bl[(s_) & 1][0];                                               \
        KF(GC, 0, 1, 0, lb_);                                                            \
        KF(GC, 2, 3, 1, lb_);                                                            \
        if (DOA) GLOADA(GC, (s_) + 3);                                                   \
        WAITV(WN);                                                                       \
        BAR;                                                                             \
    } while (0)

    // prologue: queue [B0:4][A0:4][A1:4][A2:4] -> WAITV(8) retires B0,A0 -> [A1][A2]
    STAGEB(0, 0);
    GLOADA(Ga, 0);
    GLOADA(Gb, 1);
    GLOADA(Gc, 2);
    WAITV(8);
    BAR;

    for (int s = 0; s < 27; s += 3) {    // s = 0..26; A-issue s+3 <= 29 ok
        STEP(s,     Ga, 8, 1, 1);
        STEP(s + 1, Gb, 8, 1, 1);
        STEP(s + 2, Gc, 8, 1, 1);
    }
    STEP(27, Ga, 8, 1, 1);               // issues A30
    STEP(28, Gb, 8, 1, 1);               // issues A31
    STEP(29, Gc, 4, 0, 1);               // stages B30; retires A30,B30 -> [A31]
    STEP(30, Ga, 0, 0, 1);               // stages B31; retires A31,B31 -> []
    {                                    // step 31: compute only
        const u16* lb_ = &Bl[1][0];
        KF(Gb, 0, 1, 0, lb_);
        KF(Gb, 2, 3, 1, lb_);
    }

#undef STEP
#undef KF
#undef PERM2
#undef GLOADA
#undef STAGEB

    // exact row sums: lane holds (row l31, k-half); combine halves, lanes 0-31 hold rows
    {
        float v = sm + __shfl_xor(sm, 32, 64);
        if (lane < 32) rowsum_s[wv][l31] = v;
    }

    float rcp_cp[8];
#pragma unroll
    for (int c2 = 0; c2 < 8; c2++)
        rcp_cp[c2] = 1.0f / cp[c2 * 32 + l31];

    // epilogue: tot = sum over (row,col) of [q + p*(rs - 2q)] / cp
    // C/D 32x32: col = lane&31, row = (reg&3) + 8*(reg>>2) + 4*(lane>>5)
    float tot = 0.f;
#pragma unroll
    for (int reg = 0; reg < 16; reg++) {
        const int lrow = (reg & 3) + 8 * (reg >> 2) + 4 * half;
        const float rs = rowsum_s[wv][lrow];
        const float* plrow = pl + (size_t)(m0w + lrow) * K_CL + l31;
#pragma unroll
        for (int c2 = 0; c2 < 8; c2++) {
            const float q = acc[c2][reg];
            const float p = plrow[c2 * 32];
            tot += (q + p * (rs - 2.0f * q)) * rcp_cp[c2];
        }
    }
    for (int o = 32; o; o >>= 1) tot += __shfl_down(tot, o, 64);
    if (lane == 0) red[wv] = tot;
    __syncthreads();
    if (tid == 0) atomicAdd(out, red[0] + red[1] + red[2] + red[3]);

#undef WAITV
#undef BAR
#undef SB0
}

extern "C" void kernel_launch(void* const* d_in, const int* in_sizes, int n_in,
                              void* d_out, int out_size, void* d_ws, size_t ws_size,
                              hipStream_t stream) {
    const float* w  = (const float*)d_in[0];
    const float* pl = (const float*)d_in[1];
    const float* pr = (const float*)d_in[2];
    const float* cp = (const float*)d_in[3];
    float* out = (float*)d_out;

    u16* Bpack = (u16*)d_ws;   // 4 MB

    k_prep<<<dim3(512), dim3(256), 0, stream>>>(pr, Bpack, out);
    k_main<<<dim3(64 * NSLAB), dim3(256), 0, stream>>>(w, pl, Bpack, cp, out);
}